// Round 1
// baseline (66.470 us; speedup 1.0000x reference)
//
#include <hip/hip_runtime.h>
#include <math.h>

#define LAMB    5.0f
#define LOG_2PI 1.837877066409345f
#define LOG_PI  1.144729885849400f

constexpr int HID = 100;
constexpr int KC  = 30;

__device__ __forceinline__ float softplus_f(float v) {
    // jax.nn.softplus == logaddexp(v, 0) == max(v,0) + log1p(exp(-|v|))
    return fmaxf(v, 0.0f) + log1pf(expf(-fabsf(v)));
}

__device__ __forceinline__ float student_t_lp(float xv, float df, float loc, float scale) {
    float y = (xv - loc) / scale;
    return lgammaf(0.5f * (df + 1.0f)) - lgammaf(0.5f * df)
         - 0.5f * (logf(df) + LOG_PI) - logf(scale)
         - 0.5f * (df + 1.0f) * log1pf(y * y / df);
}

__global__ __launch_bounds__(256) void vae_main(
    const float* __restrict__ x,    const float* __restrict__ eps,
    const float* __restrict__ emw1, const float* __restrict__ emb1,
    const float* __restrict__ emw2, const float* __restrict__ emb2,
    const float* __restrict__ esw1, const float* __restrict__ esb1,
    const float* __restrict__ esw2, const float* __restrict__ esb2,
    const float* __restrict__ dmw1, const float* __restrict__ dmb1,
    const float* __restrict__ dmw2, const float* __restrict__ dmb2,
    const float* __restrict__ dfw1, const float* __restrict__ dfb1,
    const float* __restrict__ dfw2, const float* __restrict__ dfb2,
    const float* __restrict__ Cc,   const float* __restrict__ Wc,
    float* __restrict__ out_xmu,   float* __restrict__ out_scale,
    float* __restrict__ out_z,     float* __restrict__ out_zmu,
    float* __restrict__ out_zstd,  float* __restrict__ partial,
    int n)
{
    const int i = blockIdx.x * 256 + threadIdx.x;

    float val = 0.0f;

    if (i < n) {
        const float2 xv = ((const float2*)x)[i];
        const float2 ev = ((const float2*)eps)[i];
        const float x0 = xv.x, x1 = xv.y;

        // ---- encoder MLPs (mu, std) fused over hidden units ----
        float m0 = 0.f, m1 = 0.f, s0 = 0.f, s1 = 0.f;
#pragma unroll 10
        for (int j = 0; j < HID; ++j) {
            float hm = fmaf(x0, emw1[j], fmaf(x1, emw1[HID + j], emb1[j]));
            hm = fmaxf(hm, 0.f);
            m0 = fmaf(hm, emw2[2 * j],     m0);
            m1 = fmaf(hm, emw2[2 * j + 1], m1);
            float hs = fmaf(x0, esw1[j], fmaf(x1, esw1[HID + j], esb1[j]));
            hs = fmaxf(hs, 0.f);
            s0 = fmaf(hs, esw2[2 * j],     s0);
            s1 = fmaf(hs, esw2[2 * j + 1], s1);
        }
        const float zmu0 = m0 + emb2[0];
        const float zmu1 = m1 + emb2[1];
        const float zstd0 = softplus_f(s0 + esb2[0]);
        const float zstd1 = softplus_f(s1 + esb2[1]);
        const float sig0 = sqrtf(zstd0);
        const float sig1 = sqrtf(zstd1);
        const float z0 = fmaf(sig0, ev.x, zmu0);
        const float z1 = fmaf(sig1, ev.y, zmu1);

        // ---- decoder MLPs (mu, df) fused ----
        float dm0 = 0.f, dm1 = 0.f, df0a = 0.f, df1a = 0.f;
#pragma unroll 10
        for (int j = 0; j < HID; ++j) {
            float hm = fmaf(z0, dmw1[j], fmaf(z1, dmw1[HID + j], dmb1[j]));
            hm = fmaxf(hm, 0.f);
            dm0 = fmaf(hm, dmw2[2 * j],     dm0);
            dm1 = fmaf(hm, dmw2[2 * j + 1], dm1);
            float hf = fmaf(z0, dfw1[j], fmaf(z1, dfw1[HID + j], dfb1[j]));
            hf = fmaxf(hf, 0.f);
            df0a = fmaf(hf, dfw2[2 * j],     df0a);
            df1a = fmaf(hf, dfw2[2 * j + 1], df1a);
        }
        const float xmu0 = dm0 + dmb2[0];
        const float xmu1 = dm1 + dmb2[1];
        const float df0 = softplus_f(df0a + dfb2[0]);
        const float df1 = softplus_f(df1a + dfb2[1]);

        // ---- RBF scale ----
        const float zz = z0 * z0 + z1 * z1;
        float a0 = 0.f, a1 = 0.f;
#pragma unroll
        for (int k = 0; k < KC; ++k) {
            const float c0 = Cc[2 * k], c1 = Cc[2 * k + 1];
            const float dk = zz + c0 * c0 + c1 * c1 - 2.0f * (z0 * c0 + z1 * c1);
            const float e = expf(-LAMB * dk);
            a0 = fmaf(e, fmaxf(Wc[2 * k],     0.f), a0);
            a1 = fmaf(e, fmaxf(Wc[2 * k + 1], 0.f), a1);
        }
        const float sc0 = 1.0f / (a0 + 1e-10f);
        const float sc1 = 1.0f / (a1 + 1e-10f);

        // ---- log p(x|z) : student-t ----
        const float log_px = student_t_lp(x0, df0, xmu0, sc0)
                           + student_t_lp(x1, df1, xmu1, sc1);

        // ---- KL = logq(z) - logp(z) ----
        const float t0 = (z0 - zmu0) / sig0;
        const float t1 = (z1 - zmu1) / sig1;
        const float lq = -0.5f * t0 * t0 - logf(sig0) - 0.5f * LOG_2PI
                       + -0.5f * t1 * t1 - logf(sig1) - 0.5f * LOG_2PI;
        const float lp = -0.5f * z0 * z0 - 0.5f * LOG_2PI
                       + -0.5f * z1 * z1 - 0.5f * LOG_2PI;
        const float kl = lq - lp;

        val = log_px - kl;

        // ---- outputs ----
        out_xmu[2 * i]     = xmu0;  out_xmu[2 * i + 1]   = xmu1;
        out_scale[2 * i]   = sc0;   out_scale[2 * i + 1] = sc1;
        out_z[2 * i]       = z0;    out_z[2 * i + 1]     = z1;
        out_zmu[2 * i]     = zmu0;  out_zmu[2 * i + 1]   = zmu1;
        out_zstd[2 * i]    = zstd0; out_zstd[2 * i + 1]  = zstd1;
    }

    // ---- deterministic block reduction of val ----
#pragma unroll
    for (int off = 32; off > 0; off >>= 1)
        val += __shfl_down(val, off, 64);

    __shared__ float wsum[4];
    const int lane = threadIdx.x & 63;
    const int wid  = threadIdx.x >> 6;
    if (lane == 0) wsum[wid] = val;
    __syncthreads();
    if (threadIdx.x == 0)
        partial[blockIdx.x] = (wsum[0] + wsum[1]) + (wsum[2] + wsum[3]);
}

__global__ __launch_bounds__(256) void vae_reduce(
    const float* __restrict__ partial, int nblk, float* __restrict__ out, int n)
{
    __shared__ double sh[256];
    double acc = 0.0;
    for (int i = threadIdx.x; i < nblk; i += 256) acc += (double)partial[i];
    sh[threadIdx.x] = acc;
    __syncthreads();
#pragma unroll
    for (int s = 128; s > 0; s >>= 1) {
        if (threadIdx.x < s) sh[threadIdx.x] += sh[threadIdx.x + s];
        __syncthreads();
    }
    if (threadIdx.x == 0) out[0] = (float)(sh[0] / (double)n);
}

extern "C" void kernel_launch(void* const* d_in, const int* in_sizes, int n_in,
                              void* d_out, int out_size, void* d_ws, size_t ws_size,
                              hipStream_t stream) {
    const float* x    = (const float*)d_in[0];
    const float* eps  = (const float*)d_in[1];
    const float* emw1 = (const float*)d_in[2];
    const float* emb1 = (const float*)d_in[3];
    const float* emw2 = (const float*)d_in[4];
    const float* emb2 = (const float*)d_in[5];
    const float* esw1 = (const float*)d_in[6];
    const float* esb1 = (const float*)d_in[7];
    const float* esw2 = (const float*)d_in[8];
    const float* esb2 = (const float*)d_in[9];
    const float* dmw1 = (const float*)d_in[10];
    const float* dmb1 = (const float*)d_in[11];
    const float* dmw2 = (const float*)d_in[12];
    const float* dmb2 = (const float*)d_in[13];
    const float* dfw1 = (const float*)d_in[14];
    const float* dfb1 = (const float*)d_in[15];
    const float* dfw2 = (const float*)d_in[16];
    const float* dfb2 = (const float*)d_in[17];
    const float* Cc   = (const float*)d_in[18];
    const float* Wc   = (const float*)d_in[19];

    const int n = in_sizes[0] / 2;      // N samples
    float* out = (float*)d_out;
    float* out_xmu   = out + 1;
    float* out_scale = out + 1 + 2 * (size_t)n;
    float* out_z     = out + 1 + 4 * (size_t)n;
    float* out_zmu   = out + 1 + 6 * (size_t)n;
    float* out_zstd  = out + 1 + 8 * (size_t)n;

    float* partial = (float*)d_ws;
    const int nblk = (n + 255) / 256;

    vae_main<<<nblk, 256, 0, stream>>>(
        x, eps,
        emw1, emb1, emw2, emb2,
        esw1, esb1, esw2, esb2,
        dmw1, dmb1, dmw2, dmb2,
        dfw1, dfb1, dfw2, dfb2,
        Cc, Wc,
        out_xmu, out_scale, out_z, out_zmu, out_zstd,
        partial, n);

    vae_reduce<<<1, 256, 0, stream>>>(partial, nblk, out, n);
}

// Round 2
// 48.844 us; speedup vs baseline: 1.3609x; 1.3609x over previous
//
#include <hip/hip_runtime.h>
#include <math.h>

#define LAMB    5.0f
#define LOG_2PI 1.837877066409345f
#define LOG_PI  1.144729885849400f
#define L2E     1.4426950408889634f
#define LN2     0.6931471805599453f

constexpr int HID = 100;
constexpr int KC  = 30;

__device__ __forceinline__ float rcp_f(float x)  { return __builtin_amdgcn_rcpf(x); }
__device__ __forceinline__ float log_f(float x)  { return __builtin_amdgcn_logf(x) * LN2; }   // ln
__device__ __forceinline__ float exp_f(float x)  { return __builtin_amdgcn_exp2f(x * L2E); }  // e^x
__device__ __forceinline__ float sqrt_f(float x) { return __builtin_amdgcn_sqrtf(x); }

// ln(1+u), safe for tiny u (where 1+u rounds to 1)
__device__ __forceinline__ float log1p_f(float u) {
    return (u > 1e-5f) ? log_f(1.0f + u) : u * (1.0f - 0.5f * u);
}

// softplus = max(v,0) + log1p(exp(-|v|))
__device__ __forceinline__ float softplus_f(float v) {
    float e = __builtin_amdgcn_exp2f(-fabsf(v) * L2E);
    return fmaxf(v, 0.0f) + log1p_f(e);
}

// Lanczos g=5, n=6 (Numerical Recipes gammln), hardware log/rcp. Valid x>0.
__device__ __forceinline__ float lgamma_f(float x) {
    float ser = 1.000000000190015f
              + 76.18009172947146f   * rcp_f(x + 1.0f)
              - 86.50532032941677f   * rcp_f(x + 2.0f)
              + 24.01409824083091f   * rcp_f(x + 3.0f)
              - 1.231739572450155f   * rcp_f(x + 4.0f)
              + 1.208650973866179e-3f* rcp_f(x + 5.0f)
              - 5.395239384953e-6f   * rcp_f(x + 6.0f);
    float t = x + 5.5f;
    return (x + 0.5f) * log_f(t) - t + log_f(2.5066282746310005f * ser * rcp_f(x));
}

// student-t log-prob with inv_std = 1/scale supplied directly
__device__ __forceinline__ float student_t_lp(float xv, float df, float loc, float inv_std) {
    float y  = (xv - loc) * inv_std;
    float u  = y * y * rcp_f(df);
    return lgamma_f(0.5f * (df + 1.0f)) - lgamma_f(0.5f * df)
         - 0.5f * (log_f(df) + LOG_PI) + log_f(inv_std)
         - 0.5f * (df + 1.0f) * log1p_f(u);
}

__global__ __launch_bounds__(256) void vae_main(
    const float* __restrict__ x,    const float* __restrict__ eps,
    const float* __restrict__ emw1, const float* __restrict__ emb1,
    const float* __restrict__ emw2, const float* __restrict__ emb2,
    const float* __restrict__ esw1, const float* __restrict__ esb1,
    const float* __restrict__ esw2, const float* __restrict__ esb2,
    const float* __restrict__ dmw1, const float* __restrict__ dmb1,
    const float* __restrict__ dmw2, const float* __restrict__ dmb2,
    const float* __restrict__ dfw1, const float* __restrict__ dfb1,
    const float* __restrict__ dfw2, const float* __restrict__ dfb2,
    const float* __restrict__ Cc,   const float* __restrict__ Wc,
    float* __restrict__ out_xmu,   float* __restrict__ out_scale,
    float* __restrict__ out_z,     float* __restrict__ out_zmu,
    float* __restrict__ out_zstd,  float* __restrict__ partial,
    int n)
{
    const int i = blockIdx.x * 256 + threadIdx.x;

    float val = 0.0f;

    if (i < n) {
        const float2 xv = ((const float2*)x)[i];
        const float2 ev = ((const float2*)eps)[i];
        const float x0 = xv.x, x1 = xv.y;

        // ---- encoder MLPs (mu, std) fused over hidden units ----
        float m0 = 0.f, m1 = 0.f, s0 = 0.f, s1 = 0.f;
#pragma unroll 10
        for (int j = 0; j < HID; ++j) {
            float hm = fmaf(x0, emw1[j], fmaf(x1, emw1[HID + j], emb1[j]));
            hm = fmaxf(hm, 0.f);
            m0 = fmaf(hm, emw2[2 * j],     m0);
            m1 = fmaf(hm, emw2[2 * j + 1], m1);
            float hs = fmaf(x0, esw1[j], fmaf(x1, esw1[HID + j], esb1[j]));
            hs = fmaxf(hs, 0.f);
            s0 = fmaf(hs, esw2[2 * j],     s0);
            s1 = fmaf(hs, esw2[2 * j + 1], s1);
        }
        const float zmu0 = m0 + emb2[0];
        const float zmu1 = m1 + emb2[1];
        const float zstd0 = softplus_f(s0 + esb2[0]);
        const float zstd1 = softplus_f(s1 + esb2[1]);
        const float sig0 = sqrt_f(zstd0);
        const float sig1 = sqrt_f(zstd1);
        const float z0 = fmaf(sig0, ev.x, zmu0);
        const float z1 = fmaf(sig1, ev.y, zmu1);

        // ---- decoder MLPs (mu, df) fused ----
        float dm0 = 0.f, dm1 = 0.f, df0a = 0.f, df1a = 0.f;
#pragma unroll 10
        for (int j = 0; j < HID; ++j) {
            float hm = fmaf(z0, dmw1[j], fmaf(z1, dmw1[HID + j], dmb1[j]));
            hm = fmaxf(hm, 0.f);
            dm0 = fmaf(hm, dmw2[2 * j],     dm0);
            dm1 = fmaf(hm, dmw2[2 * j + 1], dm1);
            float hf = fmaf(z0, dfw1[j], fmaf(z1, dfw1[HID + j], dfb1[j]));
            hf = fmaxf(hf, 0.f);
            df0a = fmaf(hf, dfw2[2 * j],     df0a);
            df1a = fmaf(hf, dfw2[2 * j + 1], df1a);
        }
        const float xmu0 = dm0 + dmb2[0];
        const float xmu1 = dm1 + dmb2[1];
        const float df0 = softplus_f(df0a + dfb2[0]);
        const float df1 = softplus_f(df1a + dfb2[1]);

        // ---- RBF inverse-scale: a = exp(-LAMB*d) @ max(W,0) ----
        // exp2 argument folded: -LAMB*L2E*(zz + c0^2+c1^2 - 2(z0 c0 + z1 c1))
        const float zz = z0 * z0 + z1 * z1;
        const float u0 = -LAMB * L2E * zz;       // constant part
        const float t0c = 2.0f * LAMB * L2E * z0;
        const float t1c = 2.0f * LAMB * L2E * z1;
        float a0 = 0.f, a1 = 0.f;
#pragma unroll
        for (int k = 0; k < KC; ++k) {
            const float c0 = Cc[2 * k], c1 = Cc[2 * k + 1];
            const float qk = fmaf(c1, c1, c0 * c0);
            const float arg = fmaf(t0c, c0, fmaf(t1c, c1, fmaf(-LAMB * L2E, qk, u0)));
            const float e = __builtin_amdgcn_exp2f(arg);
            a0 = fmaf(e, fmaxf(Wc[2 * k],     0.f), a0);
            a1 = fmaf(e, fmaxf(Wc[2 * k + 1], 0.f), a1);
        }
        const float ia0 = a0 + 1e-10f;           // inv_std
        const float ia1 = a1 + 1e-10f;
        const float sc0 = rcp_f(ia0);            // x_scale output
        const float sc1 = rcp_f(ia1);

        // ---- log p(x|z) : student-t (uses inv_std directly, no division) ----
        const float log_px = student_t_lp(x0, df0, xmu0, ia0)
                           + student_t_lp(x1, df1, xmu1, ia1);

        // ---- KL = logq(z) - logp(z); (z - zmu)/sigma == eps ----
        // kl = -0.5(e0^2+e1^2) - 0.5*(log zstd0 + log zstd1) + 0.5(z0^2+z1^2)
        const float kl = -0.5f * (ev.x * ev.x + ev.y * ev.y)
                       - 0.5f * (log_f(zstd0) + log_f(zstd1))
                       + 0.5f * zz;

        val = log_px - kl;

        // ---- outputs ----
        out_xmu[2 * i]     = xmu0;  out_xmu[2 * i + 1]   = xmu1;
        out_scale[2 * i]   = sc0;   out_scale[2 * i + 1] = sc1;
        out_z[2 * i]       = z0;    out_z[2 * i + 1]     = z1;
        out_zmu[2 * i]     = zmu0;  out_zmu[2 * i + 1]   = zmu1;
        out_zstd[2 * i]    = zstd0; out_zstd[2 * i + 1]  = zstd1;
    }

    // ---- deterministic block reduction of val ----
#pragma unroll
    for (int off = 32; off > 0; off >>= 1)
        val += __shfl_down(val, off, 64);

    __shared__ float wsum[4];
    const int lane = threadIdx.x & 63;
    const int wid  = threadIdx.x >> 6;
    if (lane == 0) wsum[wid] = val;
    __syncthreads();
    if (threadIdx.x == 0)
        partial[blockIdx.x] = (wsum[0] + wsum[1]) + (wsum[2] + wsum[3]);
}

__global__ __launch_bounds__(256) void vae_reduce(
    const float* __restrict__ partial, int nblk, float* __restrict__ out, int n)
{
    __shared__ double sh[256];
    double acc = 0.0;
    for (int i = threadIdx.x; i < nblk; i += 256) acc += (double)partial[i];
    sh[threadIdx.x] = acc;
    __syncthreads();
#pragma unroll
    for (int s = 128; s > 0; s >>= 1) {
        if (threadIdx.x < s) sh[threadIdx.x] += sh[threadIdx.x + s];
        __syncthreads();
    }
    if (threadIdx.x == 0) out[0] = (float)(sh[0] / (double)n);
}

extern "C" void kernel_launch(void* const* d_in, const int* in_sizes, int n_in,
                              void* d_out, int out_size, void* d_ws, size_t ws_size,
                              hipStream_t stream) {
    const float* x    = (const float*)d_in[0];
    const float* eps  = (const float*)d_in[1];
    const float* emw1 = (const float*)d_in[2];
    const float* emb1 = (const float*)d_in[3];
    const float* emw2 = (const float*)d_in[4];
    const float* emb2 = (const float*)d_in[5];
    const float* esw1 = (const float*)d_in[6];
    const float* esb1 = (const float*)d_in[7];
    const float* esw2 = (const float*)d_in[8];
    const float* esb2 = (const float*)d_in[9];
    const float* dmw1 = (const float*)d_in[10];
    const float* dmb1 = (const float*)d_in[11];
    const float* dmw2 = (const float*)d_in[12];
    const float* dmb2 = (const float*)d_in[13];
    const float* dfw1 = (const float*)d_in[14];
    const float* dfb1 = (const float*)d_in[15];
    const float* dfw2 = (const float*)d_in[16];
    const float* dfb2 = (const float*)d_in[17];
    const float* Cc   = (const float*)d_in[18];
    const float* Wc   = (const float*)d_in[19];

    const int n = in_sizes[0] / 2;      // N samples
    float* out = (float*)d_out;
    float* out_xmu   = out + 1;
    float* out_scale = out + 1 + 2 * (size_t)n;
    float* out_z     = out + 1 + 4 * (size_t)n;
    float* out_zmu   = out + 1 + 6 * (size_t)n;
    float* out_zstd  = out + 1 + 8 * (size_t)n;

    float* partial = (float*)d_ws;
    const int nblk = (n + 255) / 256;

    vae_main<<<nblk, 256, 0, stream>>>(
        x, eps,
        emw1, emb1, emw2, emb2,
        esw1, esb1, esw2, esb2,
        dmw1, dmb1, dmw2, dmb2,
        dfw1, dfb1, dfw2, dfb2,
        Cc, Wc,
        out_xmu, out_scale, out_z, out_zmu, out_zstd,
        partial, n);

    vae_reduce<<<1, 256, 0, stream>>>(partial, nblk, out, n);
}

// Round 3
// 45.047 us; speedup vs baseline: 1.4756x; 1.0843x over previous
//
#include <hip/hip_runtime.h>
#include <math.h>

#define LAMB    5.0f
#define LOG_2PI 1.837877066409345f
#define LOG_PI  1.144729885849400f
#define L2E     1.4426950408889634f
#define LN2     0.6931471805599453f

constexpr int HID = 100;
constexpr int KC  = 30;

typedef float v2f __attribute__((ext_vector_type(2)));

__device__ __forceinline__ float rcp_f(float x)  { return __builtin_amdgcn_rcpf(x); }
__device__ __forceinline__ v2f splat(float s)    { return (v2f){s, s}; }
__device__ __forceinline__ v2f fma2(v2f a, v2f b, v2f c) { return __builtin_elementwise_fma(a, b, c); }
__device__ __forceinline__ v2f max2(v2f a, v2f b) { return __builtin_elementwise_max(a, b); }
__device__ __forceinline__ v2f rcp2(v2f x)  { return (v2f){__builtin_amdgcn_rcpf(x.x), __builtin_amdgcn_rcpf(x.y)}; }
__device__ __forceinline__ v2f ln2v(v2f x)  { return (v2f){__builtin_amdgcn_logf(x.x), __builtin_amdgcn_logf(x.y)}; } // log2
__device__ __forceinline__ v2f lnv(v2f x)   { return ln2v(x) * splat(LN2); }                                          // ln
__device__ __forceinline__ v2f exp2v(v2f x) { return (v2f){__builtin_amdgcn_exp2f(x.x), __builtin_amdgcn_exp2f(x.y)}; }

__device__ __forceinline__ float log_f(float x)  { return __builtin_amdgcn_logf(x) * LN2; }

// ln(1+u) elementwise, safe for tiny u; branchless (cndmask)
__device__ __forceinline__ float log1p_s(float u) {
    float big = log_f(1.0f + u);
    float sml = u * (1.0f - 0.5f * u);
    return (u > 1e-5f) ? big : sml;
}
__device__ __forceinline__ v2f log1p2(v2f u) {
    return (v2f){log1p_s(u.x), log1p_s(u.y)};
}

// softplus elementwise: max(v,0) + log1p(exp(-|v|))
__device__ __forceinline__ v2f softplus2(v2f v) {
    v2f av = (v2f){fabsf(v.x), fabsf(v.y)};
    v2f e  = exp2v(av * splat(-L2E));
    return max2(v, splat(0.f)) + log1p2(e);
}

// Lanczos g=5 lgamma, packed over 2 elements. Valid x>0.
__device__ __forceinline__ v2f lgamma2(v2f x) {
    v2f ser = splat(1.000000000190015f)
            + splat(76.18009172947146f)    * rcp2(x + splat(1.0f))
            - splat(86.50532032941677f)    * rcp2(x + splat(2.0f))
            + splat(24.01409824083091f)    * rcp2(x + splat(3.0f))
            - splat(1.231739572450155f)    * rcp2(x + splat(4.0f))
            + splat(1.208650973866179e-3f) * rcp2(x + splat(5.0f))
            - splat(5.395239384953e-6f)    * rcp2(x + splat(6.0f));
    v2f t = x + splat(5.5f);
    return (x + splat(0.5f)) * lnv(t) - t + lnv(splat(2.5066282746310005f) * ser * rcp2(x));
}

__global__ __launch_bounds__(256) void vae_main(
    const float* __restrict__ x,    const float* __restrict__ eps,
    const float* __restrict__ emw1, const float* __restrict__ emb1,
    const float* __restrict__ emw2, const float* __restrict__ emb2,
    const float* __restrict__ esw1, const float* __restrict__ esb1,
    const float* __restrict__ esw2, const float* __restrict__ esb2,
    const float* __restrict__ dmw1, const float* __restrict__ dmb1,
    const float* __restrict__ dmw2, const float* __restrict__ dmb2,
    const float* __restrict__ dfw1, const float* __restrict__ dfb1,
    const float* __restrict__ dfw2, const float* __restrict__ dfb2,
    const float* __restrict__ Cc,   const float* __restrict__ Wc,
    float* __restrict__ out_xmu,   float* __restrict__ out_scale,
    float* __restrict__ out_z,     float* __restrict__ out_zmu,
    float* __restrict__ out_zstd,  float* __restrict__ partial,
    int n)
{
    const int i = blockIdx.x * 256 + threadIdx.x;

    float val = 0.0f;

    if (i < n) {
        const v2f xv = *(const v2f*)&x[2 * i];
        const v2f ev = *(const v2f*)&eps[2 * i];
        const v2f vx0 = splat(xv.x), vx1 = splat(xv.y);

        // ---- encoder MLPs (mu, std), packed over pairs of hidden units ----
        v2f accm = splat(0.f), accs = splat(0.f);   // (out0, out1) each
#pragma unroll 10
        for (int j = 0; j < HID; j += 2) {
            // mu-MLP
            v2f w1a = *(const v2f*)&emw1[j];
            v2f w1b = *(const v2f*)&emw1[HID + j];
            v2f b1  = *(const v2f*)&emb1[j];
            v2f h   = max2(fma2(vx0, w1a, fma2(vx1, w1b, b1)), splat(0.f));
            v2f w2a = *(const v2f*)&emw2[2 * j];
            v2f w2b = *(const v2f*)&emw2[2 * j + 2];
            accm = fma2(splat(h.x), w2a, accm);
            accm = fma2(splat(h.y), w2b, accm);
            // std-MLP
            v2f s1a = *(const v2f*)&esw1[j];
            v2f s1b = *(const v2f*)&esw1[HID + j];
            v2f sb1 = *(const v2f*)&esb1[j];
            v2f hs  = max2(fma2(vx0, s1a, fma2(vx1, s1b, sb1)), splat(0.f));
            v2f s2a = *(const v2f*)&esw2[2 * j];
            v2f s2b = *(const v2f*)&esw2[2 * j + 2];
            accs = fma2(splat(hs.x), s2a, accs);
            accs = fma2(splat(hs.y), s2b, accs);
        }
        const v2f vzmu  = accm + *(const v2f*)&emb2[0];
        const v2f vzstd = softplus2(accs + *(const v2f*)&esb2[0]);
        const v2f vsig  = (v2f){__builtin_amdgcn_sqrtf(vzstd.x), __builtin_amdgcn_sqrtf(vzstd.y)};
        const v2f vz    = fma2(vsig, ev, vzmu);
        const v2f vz0   = splat(vz.x), vz1 = splat(vz.y);

        // ---- decoder MLPs (mu, df), packed ----
        v2f accdm = splat(0.f), accdf = splat(0.f);
#pragma unroll 10
        for (int j = 0; j < HID; j += 2) {
            v2f w1a = *(const v2f*)&dmw1[j];
            v2f w1b = *(const v2f*)&dmw1[HID + j];
            v2f b1  = *(const v2f*)&dmb1[j];
            v2f h   = max2(fma2(vz0, w1a, fma2(vz1, w1b, b1)), splat(0.f));
            v2f w2a = *(const v2f*)&dmw2[2 * j];
            v2f w2b = *(const v2f*)&dmw2[2 * j + 2];
            accdm = fma2(splat(h.x), w2a, accdm);
            accdm = fma2(splat(h.y), w2b, accdm);

            v2f f1a = *(const v2f*)&dfw1[j];
            v2f f1b = *(const v2f*)&dfw1[HID + j];
            v2f fb1 = *(const v2f*)&dfb1[j];
            v2f hf  = max2(fma2(vz0, f1a, fma2(vz1, f1b, fb1)), splat(0.f));
            v2f f2a = *(const v2f*)&dfw2[2 * j];
            v2f f2b = *(const v2f*)&dfw2[2 * j + 2];
            accdf = fma2(splat(hf.x), f2a, accdf);
            accdf = fma2(splat(hf.y), f2b, accdf);
        }
        const v2f vxmu = accdm + *(const v2f*)&dmb2[0];
        const v2f vdf  = softplus2(accdf + *(const v2f*)&dfb2[0]);

        // ---- RBF inverse-scale: a = exp(-LAMB*d) @ max(W,0) ----
        const float zz = vz.x * vz.x + vz.y * vz.y;
        const float lam2e = LAMB * L2E;
        const float u0 = -lam2e * zz;
        const v2f tc = (v2f){2.0f * lam2e * vz.x, 2.0f * lam2e * vz.y};
        v2f a = splat(0.f);
#pragma unroll
        for (int k = 0; k < KC; ++k) {
            v2f ck = *(const v2f*)&Cc[2 * k];
            v2f wk = *(const v2f*)&Wc[2 * k];
            v2f m  = ck * fma2(splat(-lam2e), ck, tc);   // (t0 c0 - l c0^2, t1 c1 - l c1^2)
            float e = __builtin_amdgcn_exp2f(u0 + m.x + m.y);
            a = fma2(splat(e), max2(wk, splat(0.f)), a);
        }
        const v2f ia = a + splat(1e-10f);     // inv_std
        const v2f vscale = rcp2(ia);          // x_scale output

        // ---- log p(x|z): student-t, packed over dims ----
        const v2f y  = (xv - vxmu) * ia;
        const v2f u  = y * y * rcp2(vdf);
        const v2f dfp1 = vdf + splat(1.0f);
        const v2f lpx = lgamma2(splat(0.5f) * dfp1) - lgamma2(splat(0.5f) * vdf)
                      - splat(0.5f) * (lnv(vdf) + splat(LOG_PI)) + lnv(ia)
                      - splat(0.5f) * dfp1 * log1p2(u);
        const float log_px = lpx.x + lpx.y;

        // ---- KL; (z-zmu)/sigma == eps ----
        const v2f e2 = ev * ev;
        const v2f lz = lnv(vzstd);
        const float kl = -0.5f * (e2.x + e2.y) - 0.5f * (lz.x + lz.y) + 0.5f * zz;

        val = log_px - kl;

        // ---- outputs (packed stores) ----
        *(v2f*)&out_xmu[2 * i]   = vxmu;
        *(v2f*)&out_scale[2 * i] = vscale;
        *(v2f*)&out_z[2 * i]     = vz;
        *(v2f*)&out_zmu[2 * i]   = vzmu;
        *(v2f*)&out_zstd[2 * i]  = vzstd;
    }

    // ---- deterministic block reduction of val ----
#pragma unroll
    for (int off = 32; off > 0; off >>= 1)
        val += __shfl_down(val, off, 64);

    __shared__ float wsum[4];
    const int lane = threadIdx.x & 63;
    const int wid  = threadIdx.x >> 6;
    if (lane == 0) wsum[wid] = val;
    __syncthreads();
    if (threadIdx.x == 0)
        partial[blockIdx.x] = (wsum[0] + wsum[1]) + (wsum[2] + wsum[3]);
}

__global__ __launch_bounds__(256) void vae_reduce(
    const float* __restrict__ partial, int nblk, float* __restrict__ out, int n)
{
    __shared__ double sh[256];
    double acc = 0.0;
    for (int i = threadIdx.x; i < nblk; i += 256) acc += (double)partial[i];
    sh[threadIdx.x] = acc;
    __syncthreads();
#pragma unroll
    for (int s = 128; s > 0; s >>= 1) {
        if (threadIdx.x < s) sh[threadIdx.x] += sh[threadIdx.x + s];
        __syncthreads();
    }
    if (threadIdx.x == 0) out[0] = (float)(sh[0] / (double)n);
}

extern "C" void kernel_launch(void* const* d_in, const int* in_sizes, int n_in,
                              void* d_out, int out_size, void* d_ws, size_t ws_size,
                              hipStream_t stream) {
    const float* x    = (const float*)d_in[0];
    const float* eps  = (const float*)d_in[1];
    const float* emw1 = (const float*)d_in[2];
    const float* emb1 = (const float*)d_in[3];
    const float* emw2 = (const float*)d_in[4];
    const float* emb2 = (const float*)d_in[5];
    const float* esw1 = (const float*)d_in[6];
    const float* esb1 = (const float*)d_in[7];
    const float* esw2 = (const float*)d_in[8];
    const float* esb2 = (const float*)d_in[9];
    const float* dmw1 = (const float*)d_in[10];
    const float* dmb1 = (const float*)d_in[11];
    const float* dmw2 = (const float*)d_in[12];
    const float* dmb2 = (const float*)d_in[13];
    const float* dfw1 = (const float*)d_in[14];
    const float* dfb1 = (const float*)d_in[15];
    const float* dfw2 = (const float*)d_in[16];
    const float* dfb2 = (const float*)d_in[17];
    const float* Cc   = (const float*)d_in[18];
    const float* Wc   = (const float*)d_in[19];

    const int n = in_sizes[0] / 2;      // N samples
    float* out = (float*)d_out;
    float* out_xmu   = out + 1;
    float* out_scale = out + 1 + 2 * (size_t)n;
    float* out_z     = out + 1 + 4 * (size_t)n;
    float* out_zmu   = out + 1 + 6 * (size_t)n;
    float* out_zstd  = out + 1 + 8 * (size_t)n;

    float* partial = (float*)d_ws;
    const int nblk = (n + 255) / 256;

    vae_main<<<nblk, 256, 0, stream>>>(
        x, eps,
        emw1, emb1, emw2, emb2,
        esw1, esb1, esw2, esb2,
        dmw1, dmb1, dmw2, dmb2,
        dfw1, dfb1, dfw2, dfb2,
        Cc, Wc,
        out_xmu, out_scale, out_z, out_zmu, out_zstd,
        partial, n);

    vae_reduce<<<1, 256, 0, stream>>>(partial, nblk, out, n);
}